// Round 8
// baseline (277.257 us; speedup 1.0000x reference)
//
#include <hip/hip_runtime.h>

#define NN 1024
#define DD 128
#define NBLK 256

typedef __attribute__((ext_vector_type(8))) __bf16 bf16x8;
typedef __attribute__((ext_vector_type(4))) float f32x4;

__device__ __forceinline__ float us2f(unsigned short b) { return __uint_as_float(((unsigned)b) << 16); }
__device__ __forceinline__ unsigned short f2bf(float f) {
    unsigned x = __float_as_uint(f);
    return (unsigned short)((x + 0x7fffu + ((x >> 16) & 1u)) >> 16);   // RNE
}

// Grid barrier (256 blocks): 16 sub-counters (128B lines, 16 blocks each) -> master -> flag.
// tid0-only fences; RELAXED polling on one line; one acquire fence on exit.
// PROVEN protocol (rounds 2/4/7 passed on HW at 256 blocks). All blocks resident (1/CU).
__device__ __forceinline__ void gridbar(unsigned* bar, unsigned ep) {
    __syncthreads();
    if (threadIdx.x == 0) {
        __threadfence();   // release: drain this block's stores toward IC
        unsigned old = __hip_atomic_fetch_add(&bar[(blockIdx.x & 15) << 5], 1u,
                                              __ATOMIC_RELAXED, __HIP_MEMORY_SCOPE_AGENT);
        if (old == (ep << 4) - 1) {                    // 16 blocks/sub-counter done
            unsigned mold = __hip_atomic_fetch_add(&bar[512], 1u,
                                                   __ATOMIC_RELAXED, __HIP_MEMORY_SCOPE_AGENT);
            if (mold == (ep << 4) - 1)                 // all 16 sub-counters done
                __hip_atomic_store(&bar[544], ep, __ATOMIC_RELAXED, __HIP_MEMORY_SCOPE_AGENT);
        }
        while (__hip_atomic_load(&bar[544], __ATOMIC_RELAXED, __HIP_MEMORY_SCOPE_AGENT) < ep)
            __builtin_amdgcn_s_sleep(4);
        __threadfence();   // acquire: invalidate stale cached lines once
    }
    __syncthreads();
}

__global__ __launch_bounds__(1024, 4) void k_fused(
    const float* __restrict__ adj, const float* __restrict__ ew,
    const float* __restrict__ nf, const float* __restrict__ We, const float* __restrict__ be,
    const float* __restrict__ Wu, const float* __restrict__ bu,
    const float* __restrict__ Wv, const float* __restrict__ bv,
    const float* __restrict__ Wg, const float* __restrict__ bg,
    const float* __restrict__ Wc1, const float* __restrict__ bc1,
    const float* __restrict__ Wc2, const float* __restrict__ bc2,
    unsigned short* __restrict__ adjH, unsigned short* __restrict__ adjL,
    unsigned short* __restrict__ vTh0, unsigned short* __restrict__ vTl0,
    unsigned short* __restrict__ vTh1, unsigned short* __restrict__ vTl1,
    unsigned short* __restrict__ vTh2, unsigned short* __restrict__ vTl2,
    float* __restrict__ hi, float* __restrict__ hj,
    float* __restrict__ S1, float* __restrict__ S2,
    float* __restrict__ lossAcc, unsigned* __restrict__ counter,
    unsigned* __restrict__ barCnt, float* __restrict__ outL)
{
    // Row-major per-block state [4][DD]: d-consecutive lanes => conflict-free LDS.
    __shared__ float hS[4][DD], uS[4][DD], aggS[4][DD], vS[4][DD];   // 8KB
    __shared__ float gg[2][4][DD];                                   // 4KB
    __shared__ float aggP[2][4][DD];                                 // 4KB (kc-half partials)
    __shared__ float sred[2][4][2];
    __shared__ float wS[DD];
    __shared__ float hiS[64][132];    // 33.8KB, 16B-aligned rows (broadcast b128 reads)
    __shared__ float hjS[64][130];    // 33.3KB, stride 130: gcd(2,32)=2 -> b64 reads 2-way (free)
    __shared__ float lred[16];

    int tid = threadIdx.x, bx = blockIdx.x;
    int row0 = bx * 4;
    int halfq = tid >> 9, rq = (tid >> 7) & 3, d = tid & 127;   // GEMM: 1 output/thread
    int wid = tid >> 6, lane = tid & 63;
    unsigned ep = 0;

    // ---------------- Phase 0: adj -> bf16 hi/lo split (1 float4/thread, exact cover) ----------------
    {
        int idx = (bx * 1024 + tid) * 4;
        float4 a = *(const float4*)(adj + idx);
        ushort4 hv, lv;
        hv.x = f2bf(a.x); lv.x = f2bf(a.x - us2f(hv.x));
        hv.y = f2bf(a.y); lv.y = f2bf(a.y - us2f(hv.y));
        hv.z = f2bf(a.z); lv.z = f2bf(a.z - us2f(hv.z));
        hv.w = f2bf(a.w); lv.w = f2bf(a.w - us2f(hv.w));
        *(ushort4*)(adjH + idx) = hv;
        *(ushort4*)(adjL + idx) = lv;
    }
    // embed
    if (tid < 512) {
        int r = tid >> 7;
        float a = be[d];
#pragma unroll
        for (int k = 0; k < 3; ++k) a = fmaf(nf[(row0 + r) * 3 + k], We[k * DD + d], a);
        hS[r][d] = a;
    }
    __syncthreads();
    // layer-0 u/v GEMM (2 acc chains for load ILP)
    {
        const float* W = halfq ? Wv : Wu;
        float a0 = 0.f, a1 = 0.f;
#pragma unroll 2
        for (int k = 0; k < DD; k += 8) {
            f32x4 xa = *(const f32x4*)&hS[rq][k];
            f32x4 xb = *(const f32x4*)&hS[rq][k + 4];
            a0 = fmaf(xa[0], W[(k + 0) * DD + d], a0);
            a0 = fmaf(xa[1], W[(k + 1) * DD + d], a0);
            a0 = fmaf(xa[2], W[(k + 2) * DD + d], a0);
            a0 = fmaf(xa[3], W[(k + 3) * DD + d], a0);
            a1 = fmaf(xb[0], W[(k + 4) * DD + d], a1);
            a1 = fmaf(xb[1], W[(k + 5) * DD + d], a1);
            a1 = fmaf(xb[2], W[(k + 6) * DD + d], a1);
            a1 = fmaf(xb[3], W[(k + 7) * DD + d], a1);
        }
        float acc = a0 + a1;
        if (!halfq) uS[rq][d] = acc + bu[d];
        else        vS[rq][d] = acc + bv[d];
    }
    __syncthreads();
    if (tid < 128) {   // transposed bf16 hi/lo store of v (ushort4 = 4 rows at dim tid)
        ushort4 hv, lv;
        float f0 = vS[0][tid], f1 = vS[1][tid], f2 = vS[2][tid], f3 = vS[3][tid];
        hv.x = f2bf(f0); lv.x = f2bf(f0 - us2f(hv.x));
        hv.y = f2bf(f1); lv.y = f2bf(f1 - us2f(hv.y));
        hv.z = f2bf(f2); lv.z = f2bf(f2 - us2f(hv.z));
        hv.w = f2bf(f3); lv.w = f2bf(f3 - us2f(hv.w));
        *(ushort4*)(vTh0 + (size_t)tid * NN + row0) = hv;
        *(ushort4*)(vTl0 + (size_t)tid * NN + row0) = lv;
    }
    gridbar(barCnt, ++ep);

    // ---------------- 3 GCN layers: one barrier each ----------------
    for (int l = 0; l < 3; ++l) {
        const unsigned short* vh = (l == 0) ? vTh0 : (l == 1) ? vTh1 : vTh2;
        const unsigned short* vl = (l == 0) ? vTl0 : (l == 1) ? vTl1 : vTl2;
        unsigned short* vhn = (l == 0) ? vTh1 : vTh2;   // unused at l==2
        unsigned short* vln = (l == 0) ? vTl1 : vTl2;

        // ---- agg via split-bf16 MFMA (r0-proven fragments). Block computes the full 16-row
        // tile of its mt-group (4x redundant, ~free); wave wid covers nt=wid>>1, kc-half=wid&1,
        // accumulating 4 kc chunks in-register; halves reduced in LDS. No extra barrier.
        {
            int nt = wid >> 1, kcb = (wid & 1) << 2, mt = bx >> 2;
            int m = lane & 15, quad = lane >> 4;
            f32x4 acc = {0.f, 0.f, 0.f, 0.f};
            for (int kc = kcb; kc < kcb + 4; ++kc) {
                int k0 = kc * 128 + quad * 8;
                const unsigned short* ah = adjH + (size_t)(mt * 16 + m) * NN + k0;
                const unsigned short* al = adjL + (size_t)(mt * 16 + m) * NN + k0;
                const unsigned short* bh = vh + (size_t)(nt * 16 + m) * NN + k0;
                const unsigned short* bl = vl + (size_t)(nt * 16 + m) * NN + k0;
#pragma unroll
                for (int kt = 0; kt < 4; ++kt) {
                    bf16x8 aH = *(const bf16x8*)(ah + kt * 32);
                    bf16x8 aL = *(const bf16x8*)(al + kt * 32);
                    bf16x8 bH = *(const bf16x8*)(bh + kt * 32);
                    bf16x8 bL = *(const bf16x8*)(bl + kt * 32);
                    acc = __builtin_amdgcn_mfma_f32_16x16x32_bf16(aH, bH, acc, 0, 0, 0);
                    acc = __builtin_amdgcn_mfma_f32_16x16x32_bf16(aH, bL, acc, 0, 0, 0);
                    acc = __builtin_amdgcn_mfma_f32_16x16x32_bf16(aL, bH, acc, 0, 0, 0);
                }
            }
            if (quad == (bx & 3)) {   // lanes holding this block's 4 rows (rows quad*4+r of tile)
#pragma unroll
                for (int r = 0; r < 4; ++r) aggP[wid & 1][r][nt * 16 + m] = acc[r];
            }
        }
        __syncthreads();
        if (tid < 512) {
            int r = tid >> 7;
            aggS[r][d] = aggP[0][r][d] + aggP[1][r][d];
        }
        __syncthreads();
        // gate halves: gg[0] = u @ WgA, gg[1] = agg @ WgB
        {
            const float* W = Wg + l * (2 * DD * DD) + (halfq ? DD * DD : 0);
            const float (*xS)[DD] = halfq ? aggS : uS;
            float a0 = 0.f, a1 = 0.f;
#pragma unroll 2
            for (int k = 0; k < DD; k += 8) {
                f32x4 xa = *(const f32x4*)&xS[rq][k];
                f32x4 xb = *(const f32x4*)&xS[rq][k + 4];
                a0 = fmaf(xa[0], W[(k + 0) * DD + d], a0);
                a0 = fmaf(xa[1], W[(k + 1) * DD + d], a0);
                a0 = fmaf(xa[2], W[(k + 2) * DD + d], a0);
                a0 = fmaf(xa[3], W[(k + 3) * DD + d], a0);
                a1 = fmaf(xb[0], W[(k + 4) * DD + d], a1);
                a1 = fmaf(xb[1], W[(k + 5) * DD + d], a1);
                a1 = fmaf(xb[2], W[(k + 6) * DD + d], a1);
                a1 = fmaf(xb[3], W[(k + 7) * DD + d], a1);
            }
            gg[halfq][rq][d] = a0 + a1;
        }
        __syncthreads();
        if (tid < 512) {
            int r = tid >> 7;
            float g = 1.f / (1.f + __expf(-(gg[0][r][d] + gg[1][r][d] + bg[l * DD + d])));
            float nh = fmaf(g, aggS[r][d], hS[r][d]);
            hS[r][d] = nh > 0.f ? nh : 0.f;
        }
        __syncthreads();
        // next-layer u/v GEMM, or classifier head at l==2
        {
            const float* W2 = (l < 2) ? ((halfq ? Wv : Wu) + (l + 1) * DD * DD)
                                      : (Wc1 + (halfq ? DD * DD : 0));
            float a0 = 0.f, a1 = 0.f;
#pragma unroll 2
            for (int k = 0; k < DD; k += 8) {
                f32x4 xa = *(const f32x4*)&hS[rq][k];
                f32x4 xb = *(const f32x4*)&hS[rq][k + 4];
                a0 = fmaf(xa[0], W2[(k + 0) * DD + d], a0);
                a0 = fmaf(xa[1], W2[(k + 1) * DD + d], a0);
                a0 = fmaf(xa[2], W2[(k + 2) * DD + d], a0);
                a0 = fmaf(xa[3], W2[(k + 3) * DD + d], a0);
                a1 = fmaf(xb[0], W2[(k + 4) * DD + d], a1);
                a1 = fmaf(xb[1], W2[(k + 5) * DD + d], a1);
                a1 = fmaf(xb[2], W2[(k + 6) * DD + d], a1);
                a1 = fmaf(xb[3], W2[(k + 7) * DD + d], a1);
            }
            float acc = a0 + a1;
            if (l < 2) {
                if (!halfq) uS[rq][d] = acc + bu[(l + 1) * DD + d];
                else        vS[rq][d] = acc + bv[(l + 1) * DD + d];
            } else {
                float val = acc + (halfq ? 0.f : bc1[d]);
                (halfq ? hj : hi)[(size_t)(row0 + rq) * DD + d] = val;
                float p = val * Wc2[d];
#pragma unroll
                for (int off = 32; off; off >>= 1) p += __shfl_down(p, off);
                if ((tid & 63) == 0) sred[halfq][rq][(tid >> 6) & 1] = p;
            }
        }
        __syncthreads();
        if (l < 2) {
            if (tid < 128) {   // transposed bf16 hi/lo store of next v
                ushort4 hv, lv;
                float f0 = vS[0][tid], f1 = vS[1][tid], f2 = vS[2][tid], f3 = vS[3][tid];
                hv.x = f2bf(f0); lv.x = f2bf(f0 - us2f(hv.x));
                hv.y = f2bf(f1); lv.y = f2bf(f1 - us2f(hv.y));
                hv.z = f2bf(f2); lv.z = f2bf(f2 - us2f(hv.z));
                hv.w = f2bf(f3); lv.w = f2bf(f3 - us2f(hv.w));
                *(ushort4*)(vhn + (size_t)tid * NN + row0) = hv;
                *(ushort4*)(vln + (size_t)tid * NN + row0) = lv;
            }
        } else {
            if (tid < 4) S1[row0 + tid] = sred[0][tid][0] + sred[0][tid][1];
            else if (tid < 8) S2[row0 + tid - 4] = sred[1][tid - 4][0] + sred[1][tid - 4][1];
        }
        gridbar(barCnt, ++ep);
    }

    // ---------------- edge classifier: one 64x64 tile per block + loss ----------------
    {
        int i0 = (bx >> 4) << 6, j0 = (bx & 15) << 6;
        if (tid < 128) wS[tid] = Wc2[tid];
        for (int e2 = tid; e2 < 2048; e2 += 1024) {
            int r = e2 >> 5, c = (e2 & 31) << 2;
            *(f32x4*)&hiS[r][c] = *(const f32x4*)(hi + (size_t)(i0 + r) * DD + c);
            f32x4 jv = *(const f32x4*)(hj + (size_t)(j0 + r) * DD + c);
            float2 j01; j01.x = jv[0]; j01.y = jv[1];
            float2 j23; j23.x = jv[2]; j23.y = jv[3];
            *(float2*)&hjS[r][c] = j01;        // rows 8B-aligned (130*4=520B stride)
            *(float2*)&hjS[r][c + 2] = j23;
        }
        __syncthreads();
        // strided 2x2: rows (ty,ty+32) x cols (tx,tx+32); hjS via b64 -> 2-way (free)
        int ty = tid >> 5, tx = tid & 31;
        float a00 = 0.f, a01 = 0.f, a10 = 0.f, a11 = 0.f;
#pragma unroll 4
        for (int hh = 0; hh < DD; hh += 4) {
            f32x4 x0 = *(const f32x4*)&hiS[ty][hh];
            f32x4 x1 = *(const f32x4*)&hiS[ty + 32][hh];
            float2 y0a = *(const float2*)&hjS[tx][hh];
            float2 y0b = *(const float2*)&hjS[tx][hh + 2];
            float2 y1a = *(const float2*)&hjS[tx + 32][hh];
            float2 y1b = *(const float2*)&hjS[tx + 32][hh + 2];
            f32x4 w4 = *(const f32x4*)&wS[hh];
            a00 = fmaf(fabsf(x0[0] + y0a.x), w4[0], a00);
            a00 = fmaf(fabsf(x0[1] + y0a.y), w4[1], a00);
            a00 = fmaf(fabsf(x0[2] + y0b.x), w4[2], a00);
            a00 = fmaf(fabsf(x0[3] + y0b.y), w4[3], a00);
            a01 = fmaf(fabsf(x0[0] + y1a.x), w4[0], a01);
            a01 = fmaf(fabsf(x0[1] + y1a.y), w4[1], a01);
            a01 = fmaf(fabsf(x0[2] + y1b.x), w4[2], a01);
            a01 = fmaf(fabsf(x0[3] + y1b.y), w4[3], a01);
            a10 = fmaf(fabsf(x1[0] + y0a.x), w4[0], a10);
            a10 = fmaf(fabsf(x1[1] + y0a.y), w4[1], a10);
            a10 = fmaf(fabsf(x1[2] + y0b.x), w4[2], a10);
            a10 = fmaf(fabsf(x1[3] + y0b.y), w4[3], a10);
            a11 = fmaf(fabsf(x1[0] + y1a.x), w4[0], a11);
            a11 = fmaf(fabsf(x1[1] + y1a.y), w4[1], a11);
            a11 = fmaf(fabsf(x1[2] + y1b.x), w4[2], a11);
            a11 = fmaf(fabsf(x1[3] + y1b.y), w4[3], a11);
        }
        float bcv = bc2[0];
        int ia = i0 + ty, ib = ia + 32, ja = j0 + tx, jb = ja + 32;
        float s1a = S1[ia], s1b = S1[ib];
        float s2a = S2[ja], s2b = S2[jb];
        float lg00 = fmaf(0.5f, a00 + s1a + s2a, bcv);
        float lg01 = fmaf(0.5f, a01 + s1a + s2b, bcv);
        float lg10 = fmaf(0.5f, a10 + s1b + s2a, bcv);
        float lg11 = fmaf(0.5f, a11 + s1b + s2b, bcv);
        size_t o00 = (size_t)ia * NN + ja, o01 = (size_t)ia * NN + jb;
        size_t o10 = (size_t)ib * NN + ja, o11 = (size_t)ib * NN + jb;
        outL[o00] = lg00; outL[o01] = lg01; outL[o10] = lg10; outL[o11] = lg11;
        float t0 = fmaf(lg00, adj[o00], -ew[o00]);
        float t1 = fmaf(lg01, adj[o01], -ew[o01]);
        float t2 = fmaf(lg10, adj[o10], -ew[o10]);
        float t3 = fmaf(lg11, adj[o11], -ew[o11]);
        float ls = fmaf(t0, t0, fmaf(t1, t1, fmaf(t2, t2, t3 * t3)));
#pragma unroll
        for (int off = 32; off; off >>= 1) ls += __shfl_down(ls, off);
        if ((tid & 63) == 0) lred[tid >> 6] = ls;
        __syncthreads();
        if (tid == 0) {
            float bls = 0.f;
#pragma unroll
            for (int w = 0; w < 16; ++w) bls += lred[w];
            atomicAdd(lossAcc, bls);
            __threadfence();
            unsigned old = atomicAdd(counter, 1u);
            if (old == NBLK - 1u) {
                __threadfence();
                outL[(size_t)NN * NN] = (*(volatile float*)lossAcc) * (1.f / (1024.f * 1024.f));
            }
        }
    }
}

extern "C" void kernel_launch(void* const* d_in, const int* in_sizes, int n_in,
                              void* d_out, int out_size, void* d_ws, size_t ws_size,
                              hipStream_t stream)
{
    const float* nf  = (const float*)d_in[0];
    const float* adj = (const float*)d_in[1];
    const float* ew  = (const float*)d_in[2];
    const float* We  = (const float*)d_in[3];
    const float* be  = (const float*)d_in[4];
    const float* Wu  = (const float*)d_in[5];
    const float* bu  = (const float*)d_in[6];
    const float* Wv  = (const float*)d_in[7];
    const float* bv  = (const float*)d_in[8];
    const float* Wg  = (const float*)d_in[9];
    const float* bg  = (const float*)d_in[10];
    const float* Wc1 = (const float*)d_in[11];
    const float* bc1 = (const float*)d_in[12];
    const float* Wc2 = (const float*)d_in[13];
    const float* bc2 = (const float*)d_in[14];

    float* ws = (float*)d_ws;
    unsigned short* adjH = (unsigned short*)(ws);             // 1M bf16 (524288 floats)
    unsigned short* adjL = (unsigned short*)(ws + 524288);    // 1M bf16
    unsigned short* vTh0 = (unsigned short*)(ws + 1048576);   // 128K bf16 (65536 floats)
    unsigned short* vTl0 = (unsigned short*)(ws + 1114112);
    unsigned short* vTh1 = (unsigned short*)(ws + 1179648);
    unsigned short* vTl1 = (unsigned short*)(ws + 1245184);
    unsigned short* vTh2 = (unsigned short*)(ws + 1310720);
    unsigned short* vTl2 = (unsigned short*)(ws + 1376256);
    float* hi  = ws + 1441792;                       // 131072
    float* hj  = ws + 1572864;                       // 131072
    float* S1  = ws + 1703936;                       // 1024
    float* S2  = ws + 1704960;                       // 1024
    float* lossAcc = ws + 1705984;                   // 1
    unsigned* counter = (unsigned*)(ws + 1705985);   // 1
    unsigned* barCnt = (unsigned*)(ws + 1706016);    // 545 uints (sub/master/flag)

    // zero lossAcc + counter + barrier state (capture-legal)
    hipMemsetAsync((void*)lossAcc, 0, 2560, stream);
    k_fused<<<NBLK, 1024, 0, stream>>>(adj, ew, nf, We, be, Wu, bu, Wv, bv, Wg, bg,
                                       Wc1, bc1, Wc2, bc2,
                                       adjH, adjL, vTh0, vTl0, vTh1, vTl1, vTh2, vTl2,
                                       hi, hj, S1, S2,
                                       lossAcc, counter, barCnt, (float*)d_out);
}

// Round 9
// 173.964 us; speedup vs baseline: 1.5938x; 1.5938x over previous
//
#include <hip/hip_runtime.h>

#define NN 1024
#define DD 128
#define NBLK 256

typedef __attribute__((ext_vector_type(4))) float f32x4;

// Device-scope (IC write-through) store, bit-cast via unsigned for safe ISel.
__device__ __forceinline__ void scstore(float* p, float v) {
    __hip_atomic_store((unsigned*)p, __float_as_uint(v),
                       __ATOMIC_RELAXED, __HIP_MEMORY_SCOPE_AGENT);
}

// Fence-free grid barrier (256 blocks): 16 sub-counters (128B lines) -> master -> flag.
// Correctness: every cross-block buffer is write-once-then-read within the launch
// (vA/vB/vC/hi/hj/S1/S2), written via sc-stores (IC-visible at vmcnt retirement) and
// read by plain first-touch loads (no reader cached a stale copy: the address was never
// read earlier this launch, and dispatch start invalidates caches). __syncthreads drains
// each wave's vmcnt (compiler emits s_waitcnt vmcnt(0) before s_barrier), so all 1024
// threads' sc-stores are at IC before tid0's arrival atomic. NO buffer_wbl2/buffer_inv
// -> no chip-wide cache maintenance per phase (the ~20us/barrier cost in r7).
__device__ __forceinline__ void gridbar(unsigned* bar, unsigned ep) {
    __syncthreads();
    if (threadIdx.x == 0) {
        asm volatile("s_waitcnt vmcnt(0)" ::: "memory");   // belt-and-braces
        unsigned old = __hip_atomic_fetch_add(&bar[(blockIdx.x & 15) << 5], 1u,
                                              __ATOMIC_RELAXED, __HIP_MEMORY_SCOPE_AGENT);
        if (old == (ep << 4) - 1) {                        // 16 blocks/sub-counter done
            unsigned mold = __hip_atomic_fetch_add(&bar[512], 1u,
                                                   __ATOMIC_RELAXED, __HIP_MEMORY_SCOPE_AGENT);
            if (mold == (ep << 4) - 1)                     // all 16 sub-counters done
                __hip_atomic_store(&bar[544], ep, __ATOMIC_RELAXED, __HIP_MEMORY_SCOPE_AGENT);
        }
        while (__hip_atomic_load(&bar[544], __ATOMIC_RELAXED, __HIP_MEMORY_SCOPE_AGENT) < ep)
            __builtin_amdgcn_s_sleep(4);
    }
    __syncthreads();
}

__global__ __launch_bounds__(1024, 4) void k_fused(
    const float* __restrict__ adj, const float* __restrict__ ew,
    const float* __restrict__ nf, const float* __restrict__ We, const float* __restrict__ be,
    const float* __restrict__ Wu, const float* __restrict__ bu,
    const float* __restrict__ Wv, const float* __restrict__ bv,
    const float* __restrict__ Wg, const float* __restrict__ bg,
    const float* __restrict__ Wc1, const float* __restrict__ bc1,
    const float* __restrict__ Wc2, const float* __restrict__ bc2,
    float* __restrict__ vA, float* __restrict__ vB, float* __restrict__ vC,
    float* __restrict__ hi, float* __restrict__ hj,
    float* __restrict__ S1, float* __restrict__ S2,
    float* __restrict__ lossAcc, unsigned* __restrict__ counter,
    unsigned* __restrict__ barCnt, float* __restrict__ outL)
{
    // Row-major per-block state [4][DD]: d-consecutive lanes => conflict-free LDS.
    __shared__ float hS[4][DD], uS[4][DD], aggS[4][DD];     // 6KB
    __shared__ float gg[2][4][DD];                          // 4KB
    __shared__ float sred[2][4][2];
    __shared__ float wS[DD];
    __shared__ union {
        struct { float adjS[4][NN]; float pS[32][4][DD]; } g;              // 80KB
        struct { float hiS[64][132]; float hjS[64][130]; float lred[16]; } e;  // 67.1KB
    } sm;

    int tid = threadIdx.x, bx = blockIdx.x;
    int row0 = bx * 4;
    int halfq = tid >> 9, rq = (tid >> 7) & 3, d = tid & 127;   // GEMM: 1 output/thread
    unsigned ep = 0;

    // ---------------- Phase 0: stage adj rows + embed + layer-0 u/v ----------------
    {
        int r = tid >> 8, k0 = (tid & 255) << 2;
        *(f32x4*)&sm.g.adjS[r][k0] = *(const f32x4*)(adj + (size_t)(row0 + r) * NN + k0);
    }
    if (tid < 512) {
        int r = tid >> 7;
        float a = be[d];
#pragma unroll
        for (int k = 0; k < 3; ++k) a = fmaf(nf[(row0 + r) * 3 + k], We[k * DD + d], a);
        hS[r][d] = a;
    }
    __syncthreads();
    {
        const float* W = halfq ? Wv : Wu;
        float acc = 0.f;
#pragma unroll 4
        for (int k = 0; k < DD; k += 4) {
            f32x4 x4 = *(const f32x4*)&hS[rq][k];   // wave-uniform broadcast (free)
            acc = fmaf(x4[0], W[(k + 0) * DD + d], acc);
            acc = fmaf(x4[1], W[(k + 1) * DD + d], acc);
            acc = fmaf(x4[2], W[(k + 2) * DD + d], acc);
            acc = fmaf(x4[3], W[(k + 3) * DD + d], acc);
        }
        if (!halfq) uS[rq][d] = acc + bu[d];
        else        scstore(&vA[(size_t)(row0 + rq) * DD + d], acc + bv[d]);
    }
    gridbar(barCnt, ++ep);

    // ---------------- 3 GCN layers: one barrier each ----------------
    for (int l = 0; l < 3; ++l) {
        const float* vin = (l == 0) ? vA : (l == 1) ? vB : vC;
        float* vout = (l == 0) ? vB : vC;                      // unused at l==2

        // agg partials: 32 k-chunks x 32 d-quads; 16 fp32 acc regs per thread
        {
            int kk = tid >> 5, dq = tid & 31;
            int d0 = dq << 2, kb = kk << 5;
            f32x4 ac0 = {0.f,0.f,0.f,0.f}, ac1 = ac0, ac2 = ac0, ac3 = ac0;
#pragma unroll 2
            for (int ku = 0; ku < 32; ku += 4) {
                f32x4 a0 = *(const f32x4*)&sm.g.adjS[0][kb + ku];
                f32x4 a1 = *(const f32x4*)&sm.g.adjS[1][kb + ku];
                f32x4 a2 = *(const f32x4*)&sm.g.adjS[2][kb + ku];
                f32x4 a3 = *(const f32x4*)&sm.g.adjS[3][kb + ku];
#pragma unroll
                for (int j = 0; j < 4; ++j) {
                    f32x4 v4 = *(const f32x4*)(vin + (size_t)(kb + ku + j) * DD + d0);
#pragma unroll
                    for (int c = 0; c < 4; ++c) {
                        ac0[c] = fmaf(a0[j], v4[c], ac0[c]);
                        ac1[c] = fmaf(a1[j], v4[c], ac1[c]);
                        ac2[c] = fmaf(a2[j], v4[c], ac2[c]);
                        ac3[c] = fmaf(a3[j], v4[c], ac3[c]);
                    }
                }
            }
            *(f32x4*)&sm.g.pS[kk][0][d0] = ac0;
            *(f32x4*)&sm.g.pS[kk][1][d0] = ac1;
            *(f32x4*)&sm.g.pS[kk][2][d0] = ac2;
            *(f32x4*)&sm.g.pS[kk][3][d0] = ac3;
        }
        __syncthreads();
        if (tid < 512) {
            int r = tid >> 7;
            float s = 0.f;
#pragma unroll
            for (int c = 0; c < 32; ++c) s += sm.g.pS[c][r][d];
            aggS[r][d] = s;
        }
        __syncthreads();
        // gate halves: gg[0] = u @ WgA, gg[1] = agg @ WgB  (1024 threads, 1 output each)
        {
            const float* W = Wg + l * (2 * DD * DD) + (halfq ? DD * DD : 0);
            const float (*xS)[DD] = halfq ? aggS : uS;
            float acc = 0.f;
#pragma unroll 4
            for (int k = 0; k < DD; k += 4) {
                f32x4 x4 = *(const f32x4*)&xS[rq][k];
                acc = fmaf(x4[0], W[(k + 0) * DD + d], acc);
                acc = fmaf(x4[1], W[(k + 1) * DD + d], acc);
                acc = fmaf(x4[2], W[(k + 2) * DD + d], acc);
                acc = fmaf(x4[3], W[(k + 3) * DD + d], acc);
            }
            gg[halfq][rq][d] = acc;
        }
        __syncthreads();
        if (tid < 512) {
            int r = tid >> 7;
            float g = 1.f / (1.f + __expf(-(gg[0][r][d] + gg[1][r][d] + bg[l * DD + d])));
            float nh = fmaf(g, aggS[r][d], hS[r][d]);
            hS[r][d] = nh > 0.f ? nh : 0.f;
        }
        __syncthreads();
        // next-layer u/v GEMM, or classifier head at l==2
        {
            const float* W2 = (l < 2) ? ((halfq ? Wv : Wu) + (l + 1) * DD * DD)
                                      : (Wc1 + (halfq ? DD * DD : 0));
            float acc = 0.f;
#pragma unroll 4
            for (int k = 0; k < DD; k += 4) {
                f32x4 x4 = *(const f32x4*)&hS[rq][k];
                acc = fmaf(x4[0], W2[(k + 0) * DD + d], acc);
                acc = fmaf(x4[1], W2[(k + 1) * DD + d], acc);
                acc = fmaf(x4[2], W2[(k + 2) * DD + d], acc);
                acc = fmaf(x4[3], W2[(k + 3) * DD + d], acc);
            }
            if (l < 2) {
                if (!halfq) uS[rq][d] = acc + bu[(l + 1) * DD + d];
                else        scstore(&vout[(size_t)(row0 + rq) * DD + d], acc + bv[(l + 1) * DD + d]);
            } else {
                float val = acc + (halfq ? 0.f : bc1[d]);
                scstore(&(halfq ? hj : hi)[(size_t)(row0 + rq) * DD + d], val);
                float p = val * Wc2[d];
#pragma unroll
                for (int off = 32; off; off >>= 1) p += __shfl_down(p, off);
                if ((tid & 63) == 0) sred[halfq][rq][(tid >> 6) & 1] = p;
            }
        }
        if (l == 2) {
            __syncthreads();
            if (tid < 4) scstore(&S1[row0 + tid], sred[0][tid][0] + sred[0][tid][1]);
            else if (tid < 8) scstore(&S2[row0 + tid - 4], sred[1][tid - 4][0] + sred[1][tid - 4][1]);
        }
        gridbar(barCnt, ++ep);
    }

    // ---------------- edge classifier: one 64x64 tile per block + loss ----------------
    // hiS [64][132]: b128 broadcast reads (2-way, free). hjS [64][130]: 8B-aligned rows,
    // gcd(2,32)=2 -> b64 per-lane reads are 2-way (free). r8-proven: conflicts 7.9M -> 65K.
    {
        int i0 = (bx >> 4) << 6, j0 = (bx & 15) << 6;
        if (tid < 128) wS[tid] = Wc2[tid];
        for (int e2 = tid; e2 < 2048; e2 += 1024) {
            int r = e2 >> 5, c = (e2 & 31) << 2;
            *(f32x4*)&sm.e.hiS[r][c] = *(const f32x4*)(hi + (size_t)(i0 + r) * DD + c);
            f32x4 jv = *(const f32x4*)(hj + (size_t)(j0 + r) * DD + c);
            float2 j01; j01.x = jv[0]; j01.y = jv[1];
            float2 j23; j23.x = jv[2]; j23.y = jv[3];
            *(float2*)&sm.e.hjS[r][c] = j01;
            *(float2*)&sm.e.hjS[r][c + 2] = j23;
        }
        __syncthreads();
        int ty = tid >> 5, tx = tid & 31;      // strided 2x2: rows (ty,ty+32) x cols (tx,tx+32)
        float a00 = 0.f, a01 = 0.f, a10 = 0.f, a11 = 0.f;
#pragma unroll 4
        for (int hh = 0; hh < DD; hh += 4) {
            f32x4 x0 = *(const f32x4*)&sm.e.hiS[ty][hh];
            f32x4 x1 = *(const f32x4*)&sm.e.hiS[ty + 32][hh];
            float2 y0a = *(const float2*)&sm.e.hjS[tx][hh];
            float2 y0b = *(const float2*)&sm.e.hjS[tx][hh + 2];
            float2 y1a = *(const float2*)&sm.e.hjS[tx + 32][hh];
            float2 y1b = *(const float2*)&sm.e.hjS[tx + 32][hh + 2];
            f32x4 w4 = *(const f32x4*)&wS[hh];
            a00 = fmaf(fabsf(x0[0] + y0a.x), w4[0], a00);
            a00 = fmaf(fabsf(x0[1] + y0a.y), w4[1], a00);
            a00 = fmaf(fabsf(x0[2] + y0b.x), w4[2], a00);
            a00 = fmaf(fabsf(x0[3] + y0b.y), w4[3], a00);
            a01 = fmaf(fabsf(x0[0] + y1a.x), w4[0], a01);
            a01 = fmaf(fabsf(x0[1] + y1a.y), w4[1], a01);
            a01 = fmaf(fabsf(x0[2] + y1b.x), w4[2], a01);
            a01 = fmaf(fabsf(x0[3] + y1b.y), w4[3], a01);
            a10 = fmaf(fabsf(x1[0] + y0a.x), w4[0], a10);
            a10 = fmaf(fabsf(x1[1] + y0a.y), w4[1], a10);
            a10 = fmaf(fabsf(x1[2] + y0b.x), w4[2], a10);
            a10 = fmaf(fabsf(x1[3] + y0b.y), w4[3], a10);
            a11 = fmaf(fabsf(x1[0] + y1a.x), w4[0], a11);
            a11 = fmaf(fabsf(x1[1] + y1a.y), w4[1], a11);
            a11 = fmaf(fabsf(x1[2] + y1b.x), w4[2], a11);
            a11 = fmaf(fabsf(x1[3] + y1b.y), w4[3], a11);
        }
        float bcv = bc2[0];
        int ia = i0 + ty, ib = ia + 32, ja = j0 + tx, jb = ja + 32;
        float s1a = S1[ia], s1b = S1[ib];
        float s2a = S2[ja], s2b = S2[jb];
        float lg00 = fmaf(0.5f, a00 + s1a + s2a, bcv);
        float lg01 = fmaf(0.5f, a01 + s1a + s2b, bcv);
        float lg10 = fmaf(0.5f, a10 + s1b + s2a, bcv);
        float lg11 = fmaf(0.5f, a11 + s1b + s2b, bcv);
        size_t o00 = (size_t)ia * NN + ja, o01 = (size_t)ia * NN + jb;
        size_t o10 = (size_t)ib * NN + ja, o11 = (size_t)ib * NN + jb;
        outL[o00] = lg00; outL[o01] = lg01; outL[o10] = lg10; outL[o11] = lg11;
        float t0 = fmaf(lg00, adj[o00], -ew[o00]);
        float t1 = fmaf(lg01, adj[o01], -ew[o01]);
        float t2 = fmaf(lg10, adj[o10], -ew[o10]);
        float t3 = fmaf(lg11, adj[o11], -ew[o11]);
        float ls = fmaf(t0, t0, fmaf(t1, t1, fmaf(t2, t2, t3 * t3)));
#pragma unroll
        for (int off = 32; off; off >>= 1) ls += __shfl_down(ls, off);
        if ((tid & 63) == 0) sm.e.lred[tid >> 6] = ls;
        __syncthreads();
        if (tid == 0) {
            float bls = 0.f;
#pragma unroll
            for (int w = 0; w < 16; ++w) bls += sm.e.lred[w];
            atomicAdd(lossAcc, bls);                           // device-coherent RMW at IC
            asm volatile("s_waitcnt vmcnt(0)" ::: "memory");   // my add is at IC
            unsigned old = atomicAdd(counter, 1u);
            if (old == NBLK - 1u) {                            // all 256 adds at IC
                unsigned Lb = __hip_atomic_load((unsigned*)lossAcc,
                                                __ATOMIC_RELAXED, __HIP_MEMORY_SCOPE_AGENT);
                outL[(size_t)NN * NN] = __uint_as_float(Lb) * (1.f / (1024.f * 1024.f));
            }
        }
    }
}

extern "C" void kernel_launch(void* const* d_in, const int* in_sizes, int n_in,
                              void* d_out, int out_size, void* d_ws, size_t ws_size,
                              hipStream_t stream)
{
    const float* nf  = (const float*)d_in[0];
    const float* adj = (const float*)d_in[1];
    const float* ew  = (const float*)d_in[2];
    const float* We  = (const float*)d_in[3];
    const float* be  = (const float*)d_in[4];
    const float* Wu  = (const float*)d_in[5];
    const float* bu  = (const float*)d_in[6];
    const float* Wv  = (const float*)d_in[7];
    const float* bv  = (const float*)d_in[8];
    const float* Wg  = (const float*)d_in[9];
    const float* bg  = (const float*)d_in[10];
    const float* Wc1 = (const float*)d_in[11];
    const float* bc1 = (const float*)d_in[12];
    const float* Wc2 = (const float*)d_in[13];
    const float* bc2 = (const float*)d_in[14];

    float* ws = (float*)d_ws;
    float* vA  = ws;                                 // 131072  (write-once: phase0)
    float* vB  = ws + 131072;                        // 131072  (write-once: layer0)
    float* vC  = ws + 262144;                        // 131072  (write-once: layer1)
    float* hi  = ws + 393216;                        // 131072  (write-once: layer2)
    float* hj  = ws + 524288;                        // 131072  (write-once: layer2)
    float* S1  = ws + 655360;                        // 1024
    float* S2  = ws + 656384;                        // 1024
    float* lossAcc = ws + 657408;                    // 1
    unsigned* counter = (unsigned*)(ws + 657409);    // 1
    unsigned* barCnt = (unsigned*)(ws + 657440);     // 545 uints (sub/master/flag)

    // zero lossAcc + counter + barrier state (capture-legal)
    hipMemsetAsync((void*)lossAcc, 0, 2560, stream);
    k_fused<<<NBLK, 1024, 0, stream>>>(adj, ew, nf, We, be, Wu, bu, Wv, bv, Wg, bg,
                                       Wc1, bc1, Wc2, bc2, vA, vB, vC, hi, hj, S1, S2,
                                       lossAcc, counter, barCnt, (float*)d_out);
}